// Round 1
// baseline (114.944 us; speedup 1.0000x reference)
//
#include <hip/hip_runtime.h>

// Residual_Binary: fused byte-wise xnor/and/or + swap(half-row) + even/odd
// de-interleave, applied twice. Row-local -> single pass, packed 4 bytes/dword.
//
// Identities used (all of w1,w2,b1,b2 have bytes in {0,255}):
//   z1 = (~(x^w1))&0xFF & b1          = (x & b1) ^ (~w1 & b1)        = (x&B1)^C1
//   z2 = ((~(t^w2))&0xFF) | b2        = (t & ~b2) ^ (((~w2)&~b2)|b2) = (t&M2)^C2
//   swap: byte index j -> j ^ 4096          (word index m -> m ^ 1024)
//   transpose2: t[k]=y[2k] (k<4096), t[4096+k]=y[2k+1]  -> one v_perm per word

constexpr int W     = 8192;   // row width in elements (bytes)
constexpr int WORDS = 2048;   // packed dwords per row
constexpr int HALF  = 1024;   // half row in words

static __device__ __forceinline__ unsigned int perm_b32(unsigned int hi, unsigned int lo, unsigned int sel) {
    return __builtin_amdgcn_perm(hi, lo, sel);
}

static __device__ __forceinline__ unsigned int pack4(uint4 v) {
    return (v.x & 0xFFu) | ((v.y & 0xFFu) << 8) | ((v.z & 0xFFu) << 16) | ((v.w & 0xFFu) << 24);
}

__global__ __launch_bounds__(256)
void residual_binary_kernel(const int* __restrict__ x,
                            const int* __restrict__ w1, const int* __restrict__ w2,
                            const int* __restrict__ b1, const int* __restrict__ b2,
                            int* __restrict__ out, int rows_per_block)
{
    __shared__ unsigned int Xs[WORDS];
    __shared__ unsigned int Ts[WORDS];

    const int t = threadIdx.x;

    // --- per-thread packed constants (once per block; same columns every row) ---
    // stage q (q=0..3) consumes swap-side words (2t+512q)^1024 and +1
    unsigned B1p[4][2], C1p[4][2], M2p[4][2], C2p[4][2];
#pragma unroll
    for (int q = 0; q < 4; ++q) {
        const int m = (2 * t + 512 * q) ^ HALF;
#pragma unroll
        for (int j = 0; j < 2; ++j) {
            const int e = 4 * (m + j);
            unsigned pb1 = pack4(*(const uint4*)(b1 + e));
            unsigned pw1 = pack4(*(const uint4*)(w1 + e));
            unsigned pb2 = pack4(*(const uint4*)(b2 + e));
            unsigned pw2 = pack4(*(const uint4*)(w2 + e));
            B1p[q][j] = pb1;
            C1p[q][j] = (~pw1) & pb1;
            M2p[q][j] = ~pb2;
            C2p[q][j] = ((~pw2) & (~pb2)) | pb2;
        }
    }

    const unsigned sel_even = 0x06040200u;  // bytes 0,2 of lo then 0,2 of hi
    const unsigned sel_odd  = 0x07050301u;  // bytes 1,3 of lo then 1,3 of hi

    long long row = (long long)blockIdx.x * rows_per_block;
    for (int r = 0; r < rows_per_block; ++r, ++row) {
        const int* xrow = x + row * (long long)W;
        int*       orow = out + row * (long long)W;

        // pack x row into LDS (loads per-instruction contiguous: 1KB/wave)
#pragma unroll
        for (int i = 0; i < 8; ++i) {
            const int widx = t + 256 * i;
            Xs[widx] = pack4(*(const uint4*)(xrow + 4 * widx));
        }
        __syncthreads();

        // stage 1: y = x | swap(z1);  Ts = transpose2(y)
#pragma unroll
        for (int q = 0; q < 4; ++q) {
            const int m = 2 * t + 512 * q;
            uint2 xa = *(const uint2*)&Xs[m];
            uint2 xs = *(const uint2*)&Xs[m ^ HALF];
            unsigned y0 = xa.x | ((xs.x & B1p[q][0]) ^ C1p[q][0]);
            unsigned y1 = xa.y | ((xs.y & B1p[q][1]) ^ C1p[q][1]);
            const int K = t + 256 * q;          // t-word in even half; K+HALF odd half
            Ts[K]        = perm_b32(y1, y0, sel_even);
            Ts[K + HALF] = perm_b32(y1, y0, sel_odd);
        }
        __syncthreads();

        // stage 2: u = t & swap(z2);  out = transpose2(u), unpack to int32
#pragma unroll
        for (int q = 0; q < 4; ++q) {
            const int m = 2 * t + 512 * q;
            uint2 ta = *(const uint2*)&Ts[m];
            uint2 ts = *(const uint2*)&Ts[m ^ HALF];
            unsigned u0 = ta.x & ((ts.x & M2p[q][0]) ^ C2p[q][0]);
            unsigned u1 = ta.y & ((ts.y & M2p[q][1]) ^ C2p[q][1]);
            const int K = t + 256 * q;
            unsigned oe = perm_b32(u1, u0, sel_even);
            unsigned oo = perm_b32(u1, u0, sel_odd);
            *(int4*)(orow + 4 * K) =
                make_int4((int)(oe & 0xFF), (int)((oe >> 8) & 0xFF),
                          (int)((oe >> 16) & 0xFF), (int)(oe >> 24));
            *(int4*)(orow + 4 * (K + HALF)) =
                make_int4((int)(oo & 0xFF), (int)((oo >> 8) & 0xFF),
                          (int)((oo >> 16) & 0xFF), (int)(oo >> 24));
        }
        __syncthreads();   // protect Ts against next row's stage-1 writes
    }
}

extern "C" void kernel_launch(void* const* d_in, const int* in_sizes, int n_in,
                              void* d_out, int out_size, void* d_ws, size_t ws_size,
                              hipStream_t stream) {
    const int* x  = (const int*)d_in[0];
    const int* w1 = (const int*)d_in[1];
    const int* w2 = (const int*)d_in[2];
    const int* b1 = (const int*)d_in[3];
    const int* b2 = (const int*)d_in[4];
    int* out = (int*)d_out;

    const int rows = in_sizes[0] / W;        // 8192
    const int RPB  = 4;                      // rows per block
    const int grid = rows / RPB;             // 2048 blocks x 256 threads
    residual_binary_kernel<<<grid, 256, 0, stream>>>(x, w1, w2, b1, b2, out, RPB);
}